// Round 5
// baseline (448.877 us; speedup 1.0000x reference)
//
#include <hip/hip_runtime.h>
#include <math.h>

// Batched expm of 4x4 fp32 matrices: out[m] = expm(A[m] * t[m / S]).
//
// R4 = R3 with the compile fix: nontemporal stores go through a clang
// ext_vector_type(4) pointer (HIP's float4 class type is rejected by
// __builtin_nontemporal_store).
//
// Design: K=4 matrices per thread, all pipeline stages looped over K
// innermost -> 4 independent dependency chains interleaved (hides packed-FMA
// chain latency that R0-R2 stalled on) and 16 independent global loads in
// flight per thread (4x memory-level parallelism). No LDS (R2 proved access
// pattern is not the limiter). Nontemporal stores preserve LLC for input.
//
// Math (matches reference structure):
//   s = clip(ceil(log2(max(||Qt||_inf,1e-30)/0.5)), 0, 16)
//   Xs = Qt * 2^-s ; P = Taylor_8(Xs) via Paterson-Stockmeyer (4 matmuls);
//   P = P^(2^s).  Taylor tail 0.5^9/9! ~ 5e-9 << fp32 eps.

typedef float v2f __attribute__((ext_vector_type(2)));
typedef float v4f __attribute__((ext_vector_type(4)));

constexpr int K = 4;

// C += A * B for 4x4 stored as [row][pair] of float2 (pair 0 = cols 0..1).
__device__ __forceinline__ void mm4(const v2f (&Am)[4][2],
                                    const v2f (&Bm)[4][2],
                                    v2f (&Cm)[4][2])
{
#pragma unroll
    for (int i = 0; i < 4; ++i) {
        const float a0 = Am[i][0][0], a1 = Am[i][0][1];
        const float a2 = Am[i][1][0], a3 = Am[i][1][1];
#pragma unroll
        for (int p = 0; p < 2; ++p) {
            v2f acc = Cm[i][p];
            acc += a0 * Bm[0][p];
            acc += a1 * Bm[1][p];
            acc += a2 * Bm[2][p];
            acc += a3 * Bm[3][p];
            Cm[i][p] = acc;
        }
    }
}

template <int KK>
__device__ __forceinline__ void expm_run(const float* __restrict__ A,
                                         const float* __restrict__ tvec,
                                         float* __restrict__ out,
                                         int m0, int S)
{
    // batch index for matrix m0 (one int division, amortized over KK)
    const int q = m0 / S;
    const int r = m0 - q * S;

    // ---- issue all KK*4 independent loads up front ----
    const v4f* Ap = reinterpret_cast<const v4f*>(A) + (size_t)m0 * 4;
    v4f L[KK][4];
#pragma unroll
    for (int k = 0; k < KK; ++k)
#pragma unroll
        for (int i = 0; i < 4; ++i)
            L[k][i] = Ap[4 * k + i];

    constexpr float c2 = 1.f/2.f,   c3 = 1.f/6.f,    c4 = 1.f/24.f;
    constexpr float c5 = 1.f/120.f, c6 = 1.f/720.f,  c7 = 1.f/5040.f;
    constexpr float c8 = 1.f/40320.f;

    v2f X[KK][4][2], X2[KK][4][2], X3[KK][4][2], T1[KK][4][2], P[KK][4][2];
    int si[KK];

    // ---- scale: X = Qt * 2^-s ----
#pragma unroll
    for (int k = 0; k < KK; ++k) {
        const float t = tvec[q + ((r + k) >= S ? 1 : 0)];
        float nrm = 0.0f;
#pragma unroll
        for (int i = 0; i < 4; ++i) {
            float rs = fabsf(L[k][i][0]) + fabsf(L[k][i][1])
                     + fabsf(L[k][i][2]) + fabsf(L[k][i][3]);
            nrm = fmaxf(nrm, rs);
        }
        float sf = ceilf(log2f(fmaxf(t * nrm, 1e-30f) * 2.0f));  // log2(||Qt||/0.5)
        sf = fminf(fmaxf(sf, 0.0f), 16.0f);
        si[k] = (int)sf;
        const float c = t * ldexpf(1.0f, -si[k]);
#pragma unroll
        for (int i = 0; i < 4; ++i) {
            X[k][i][0] = v2f{L[k][i][0], L[k][i][1]} * c;
            X[k][i][1] = v2f{L[k][i][2], L[k][i][3]} * c;
        }
    }

    // ---- powers (K-interleaved chains) ----
#pragma unroll
    for (int k = 0; k < KK; ++k) {
#pragma unroll
        for (int i = 0; i < 4; ++i) { X2[k][i][0] = v2f{0.f,0.f}; X2[k][i][1] = v2f{0.f,0.f}; }
        mm4(X[k], X[k], X2[k]);
    }
#pragma unroll
    for (int k = 0; k < KK; ++k) {
#pragma unroll
        for (int i = 0; i < 4; ++i) { X3[k][i][0] = v2f{0.f,0.f}; X3[k][i][1] = v2f{0.f,0.f}; }
        mm4(X2[k], X[k], X3[k]);
    }

    // ---- T1 = B1 + X3*B2 ;  P = B0 + X3*T1 ----
#pragma unroll
    for (int k = 0; k < KK; ++k) {
        v2f B2[4][2];
#pragma unroll
        for (int i = 0; i < 4; ++i)
#pragma unroll
            for (int p = 0; p < 2; ++p) B2[i][p] = c7 * X[k][i][p] + c8 * X2[k][i][p];
        B2[0][0][0] += c6; B2[1][0][1] += c6; B2[2][1][0] += c6; B2[3][1][1] += c6;

#pragma unroll
        for (int i = 0; i < 4; ++i)
#pragma unroll
            for (int p = 0; p < 2; ++p) T1[k][i][p] = c4 * X[k][i][p] + c5 * X2[k][i][p];
        T1[k][0][0][0] += c3; T1[k][1][0][1] += c3; T1[k][2][1][0] += c3; T1[k][3][1][1] += c3;
        mm4(X3[k], B2, T1[k]);
    }
#pragma unroll
    for (int k = 0; k < KK; ++k) {
#pragma unroll
        for (int i = 0; i < 4; ++i)
#pragma unroll
            for (int p = 0; p < 2; ++p) P[k][i][p] = X[k][i][p] + c2 * X2[k][i][p];
        P[k][0][0][0] += 1.f; P[k][1][0][1] += 1.f; P[k][2][1][0] += 1.f; P[k][3][1][1] += 1.f;
        mm4(X3[k], T1[k], P[k]);
    }

    // ---- undo scaling: per-matrix divergent squaring count ----
#pragma unroll
    for (int k = 0; k < KK; ++k) {
        for (int it = 0; it < si[k]; ++it) {
            v2f Q[4][2] = {};
            mm4(P[k], P[k], Q);
#pragma unroll
            for (int i = 0; i < 4; ++i) { P[k][i][0] = Q[i][0]; P[k][i][1] = Q[i][1]; }
        }
    }

    // ---- stores (nontemporal: output is never re-read) ----
    v4f* Og = reinterpret_cast<v4f*>(out) + (size_t)m0 * 4;
#pragma unroll
    for (int k = 0; k < KK; ++k)
#pragma unroll
        for (int i = 0; i < 4; ++i) {
            v4f v = {P[k][i][0][0], P[k][i][0][1],
                     P[k][i][1][0], P[k][i][1][1]};
            __builtin_nontemporal_store(v, Og + 4 * k + i);
        }
}

__global__ void __launch_bounds__(256, 2) expm4_kernel(
    const float* __restrict__ A,
    const float* __restrict__ tvec,
    float* __restrict__ out,
    int M, int S)
{
    const int tid = blockIdx.x * 256 + threadIdx.x;
    int m0 = tid * K;
    if (m0 >= M) return;

    if (m0 + K <= M) {
        expm_run<K>(A, tvec, out, m0, S);
    } else {
        for (; m0 < M; ++m0) expm_run<1>(A, tvec, out, m0, S);
    }
}

extern "C" void kernel_launch(void* const* d_in, const int* in_sizes, int n_in,
                              void* d_out, int out_size, void* d_ws, size_t ws_size,
                              hipStream_t stream) {
    const float* A    = (const float*)d_in[0];   // [B, S, 4, 4] fp32
    const float* tvec = (const float*)d_in[1];   // [B] fp32
    float* out        = (float*)d_out;           // [B, S, 4, 4] fp32

    const int B = in_sizes[1];
    const int M = in_sizes[0] / 16;              // total 4x4 matrices
    const int S = M / B;                         // matrices per batch item

    const int threads = 256;
    const int matPerBlock = threads * K;
    const int blocks = (M + matPerBlock - 1) / matPerBlock;
    expm4_kernel<<<blocks, threads, 0, stream>>>(A, tvec, out, M, S);
}